// Round 14
// baseline (563.457 us; speedup 1.0000x reference)
//
#include <hip/hip_runtime.h>
#include <hip/hip_bf16.h>

#define Nn 100000
#define Ee 1600000
#define Hh 128
#define Gg 1000
#define EPSb 1e-5f

#define AGG_BLOCKS 2048
#define NWAVES (AGG_BLOCKS * 4)   // 8192
#define GEMM_BLOCKS 782     // ceil(100000/128)

#define BKT 196             // buckets = ceil(100000/512)
#define BSTRIDE 12288       // staging slots per bucket (mean 8163, +45 sigma)
#define FILL_CHUNK 4096
#define FILL_BLOCKS 391     // ceil(1600000/4096)

typedef unsigned int uint;
typedef short short8 __attribute__((ext_vector_type(8)));
typedef float floatx4 __attribute__((ext_vector_type(4)));

// round-to-nearest-even f32 -> bf16 (as low 16 bits of return)
static __device__ __forceinline__ uint bf16rne(float f) {
    uint u = __float_as_uint(f);
    return (u + 0x7fffu + ((u >> 16) & 1u)) >> 16;
}
static __device__ __forceinline__ float bflo(uint u) { return __uint_as_float(u << 16); }
static __device__ __forceinline__ float bfhi(uint u) { return __uint_as_float(u & 0xffff0000u); }

// ---------------- graph preprocessing ----------------
// deg/bcnt/colsum zeroed by one hipMemsetAsync. deg counted inside k_bucket.
// offs = CSR over in-edges only; self-loop handled in k_agg; dinv=rsqrt(deg+1).
// dinv factorization: GEMM pre-scales rows by dinv[src]; k_agg applies dinv[d].

// pass A: privatized counting sort by dst>>9 + per-node degree atomics.
__global__ __launch_bounds__(256) void k_bucket(
    const int* __restrict__ src, const int* __restrict__ dst,
    int* __restrict__ deg, int* __restrict__ bcnt, uint* __restrict__ stage) {
    __shared__ int cnt[BKT];
    __shared__ int base[BKT];
    int t = threadIdx.x;
    if (t < BKT) cnt[t] = 0;
    __syncthreads();
    int e0 = blockIdx.x * FILL_CHUNK;
    int slot[16], bkt[16];
#pragma unroll
    for (int j = 0; j < 16; ++j) {
        int i = e0 + j * 256 + t;
        if (i < Ee) {
            int dd = dst[i];
            atomicAdd(&deg[dd], 1);           // folded k_deg
            int b = dd >> 9;
            bkt[j] = b;
            slot[j] = atomicAdd(&cnt[b], 1);
        } else bkt[j] = -1;
    }
    __syncthreads();
    if (t < BKT) base[t] = atomicAdd(&bcnt[t], cnt[t]);
    __syncthreads();
#pragma unroll
    for (int j = 0; j < 16; ++j) {
        if (bkt[j] >= 0) {
            int i = e0 + j * 256 + t;
            int b = bkt[j];
            int p = base[b] + slot[j];
            if (p < BSTRIDE)
                stage[(size_t)b * BSTRIDE + p] =
                    (uint)src[i] | (((uint)dst[i] & 511u) << 17);
        }
    }
}

// prep: fused scan (offs + dinv) + scatter for one bucket (512 nodes).
// Bucket base = in-LDS scan of bcnt; local offs kept in LDS for the scatter.
__global__ __launch_bounds__(256) void k_prep(
    const int* __restrict__ deg, const int* __restrict__ bcnt,
    const uint* __restrict__ stage,
    int* __restrict__ offs, float* __restrict__ dinv, int* __restrict__ adj) {
    __shared__ int ls[256];
    __shared__ int bs[256];
    __shared__ int loffs[512];
    __shared__ int lcur[512];
    int t = threadIdx.x;
    int b = blockIdx.x;                 // bucket 0..195
    lcur[t] = 0; lcur[t + 256] = 0;
    bs[t] = (t < BKT) ? bcnt[t] : 0;
    int nEdges = bcnt[b];
    int base = (b << 9) + t * 2;        // 2 nodes per thread
    int d0 = (base     < Nn) ? deg[base]     : 0;
    int d1 = (base + 1 < Nn) ? deg[base + 1] : 0;
    int s = d0 + d1;
    ls[t] = s;
    __syncthreads();
    for (int off = 1; off < 256; off <<= 1) {
        int u0 = (t >= off) ? bs[t - off] : 0;
        int u1 = (t >= off) ? ls[t - off] : 0;
        __syncthreads();
        bs[t] += u0;
        ls[t] += u1;
        __syncthreads();
    }
    int bucketBase = (b == 0) ? 0 : bs[b - 1];
    int run = bucketBase + ls[t] - s;   // exclusive prefix
    loffs[t * 2] = run;
    if (base < Nn) {
        offs[base] = run;
        dinv[base] = rsqrtf((float)(d0 + 1));
    }
    run += d0;
    loffs[t * 2 + 1] = run;
    if (base + 1 < Nn) {
        offs[base + 1] = run;
        dinv[base + 1] = rsqrtf((float)(d1 + 1));
    }
    if (b == 0 && t == 0) offs[Nn] = Ee;
    __syncthreads();
    int n = nEdges > BSTRIDE ? BSTRIDE : nEdges;
    const uint* sp = stage + (size_t)b * BSTRIDE;
    for (int i = t; i < n; i += 256) {
        uint e = sp[i];
        int s2 = (int)(e & 0x1FFFFu);
        int dl = (int)(e >> 17);
        int pos = loffs[dl] + atomicAdd(&lcur[dl], 1);
        adj[pos] = s2;
    }
}

// ------- W conversion (all 3 layers): Wt[l][n][k/2] = bf16(W[k][n],W[k+1][n]) --

__global__ void k_wconv3(const float* __restrict__ W1, const float* __restrict__ W2,
                         const float* __restrict__ W3, uint* __restrict__ Wt) {
    int idx = blockIdx.x * blockDim.x + threadIdx.x;   // 3*8192
    if (idx >= 3 * 8192) return;
    const float* W = (idx < 8192) ? W1 : ((idx < 16384) ? W2 : W3);
    int k = idx & 8191;
    int n = k >> 6, ku = k & 63;
    uint lo = bf16rne(W[(size_t)(2 * ku) * 128 + n]);
    uint hi = bf16rne(W[(size_t)(2 * ku + 1) * 128 + n]);
    Wt[(size_t)(idx >> 13) * 8192 + n * 64 + ku] = lo | (hi << 16);
}

// ---------------- MFMA GEMM (barrier-free, register-direct) ----------------
// tmp(bf16) = dinv[node] * (act(in) @ W).
// No X/W LDS staging: each lane loads its 16B MFMA fragments directly from
// global (X rows and Wt rows are contiguous); W is L2-broadcast, X's second
// read (two feature-half waves) is L2-hot. LDS only holds the 1KB BN affine.
// mode 0: in = fp32 x, identity act. mode 1: in = bf16 agg, act = relu(bn).

__global__ __launch_bounds__(256) void k_gemm(
    const float* __restrict__ inf, const uint* __restrict__ inb,
    const uint* __restrict__ Wtp, const float* __restrict__ dinv,
    const float* __restrict__ cs, const float* __restrict__ gg,
    const float* __restrict__ be,
    uint* __restrict__ outb, int mode) {
    __shared__ __attribute__((aligned(16))) float scsh[256];   // sc[128], sh[128]
    int t = threadIdx.x;
    if (mode) {
        if (t < 128) {
            float s = cs[t], q = cs[128 + t];
            float m = s * (1.0f / Nn);
            float var = q * (1.0f / Nn) - m * m;
            float istd = rsqrtf(var + EPSb);
            float sc = istd * gg[t];
            scsh[t] = sc;
            scsh[128 + t] = fmaf(-m, sc, be[t]);
        }
        __syncthreads();
    }

    int l = t & 63, w = t >> 6;
    int rowBase = blockIdx.x * 128;
    int nb = (w >> 1) * 64;       // node-tile base
    int fb2 = (w & 1) * 64;       // feature-tile base
    int lr = l & 15, lk = l >> 4;

    int nd[4];
#pragma unroll
    for (int mi = 0; mi < 4; ++mi) {
        int node = rowBase + nb + mi * 16 + lr;
        nd[mi] = node < Nn ? node : Nn - 1;
    }

    floatx4 zero = {0.f, 0.f, 0.f, 0.f};
    floatx4 acc[4][4];
#pragma unroll
    for (int mi = 0; mi < 4; ++mi)
#pragma unroll
        for (int ni = 0; ni < 4; ++ni) acc[mi][ni] = zero;

#pragma unroll
    for (int kc = 0; kc < 4; ++kc) {
        int g = kc * 4 + lk;            // 16B fragment index, k = g*8..g*8+7
        short8 xf[4], wf[4];
        if (mode == 0) {
#pragma unroll
            for (int mi = 0; mi < 4; ++mi) {
                const float* sp = inf + (size_t)nd[mi] * 128 + g * 8;
                float4 v0 = *(const float4*)sp;
                float4 v1 = *(const float4*)(sp + 4);
                uint4 o;
                o.x = bf16rne(v0.x) | (bf16rne(v0.y) << 16);
                o.y = bf16rne(v0.z) | (bf16rne(v0.w) << 16);
                o.z = bf16rne(v1.x) | (bf16rne(v1.y) << 16);
                o.w = bf16rne(v1.z) | (bf16rne(v1.w) << 16);
                union { uint4 u; short8 s; } cvt;
                cvt.u = o;
                xf[mi] = cvt.s;
            }
        } else {
            float4 s0 = *(const float4*)(scsh + g * 8);
            float4 s1 = *(const float4*)(scsh + g * 8 + 4);
            float4 h0 = *(const float4*)(scsh + 128 + g * 8);
            float4 h1 = *(const float4*)(scsh + 128 + g * 8 + 4);
#pragma unroll
            for (int mi = 0; mi < 4; ++mi) {
                uint4 v = *(const uint4*)(inb + (size_t)nd[mi] * 64 + g * 4);
                float a0 = fmaxf(fmaf(bflo(v.x), s0.x, h0.x), 0.f);
                float a1 = fmaxf(fmaf(bfhi(v.x), s0.y, h0.y), 0.f);
                float a2 = fmaxf(fmaf(bflo(v.y), s0.z, h0.z), 0.f);
                float a3 = fmaxf(fmaf(bfhi(v.y), s0.w, h0.w), 0.f);
                float a4 = fmaxf(fmaf(bflo(v.z), s1.x, h1.x), 0.f);
                float a5 = fmaxf(fmaf(bfhi(v.z), s1.y, h1.y), 0.f);
                float a6 = fmaxf(fmaf(bflo(v.w), s1.z, h1.z), 0.f);
                float a7 = fmaxf(fmaf(bfhi(v.w), s1.w, h1.w), 0.f);
                uint4 o;
                o.x = bf16rne(a0) | (bf16rne(a1) << 16);
                o.y = bf16rne(a2) | (bf16rne(a3) << 16);
                o.z = bf16rne(a4) | (bf16rne(a5) << 16);
                o.w = bf16rne(a6) | (bf16rne(a7) << 16);
                union { uint4 u; short8 s; } cvt;
                cvt.u = o;
                xf[mi] = cvt.s;
            }
        }
#pragma unroll
        for (int ni = 0; ni < 4; ++ni)
            wf[ni] = *(const short8*)(Wtp + (size_t)(fb2 + ni * 16 + lr) * 64 + g * 4);
#pragma unroll
        for (int mi = 0; mi < 4; ++mi)
#pragma unroll
            for (int ni = 0; ni < 4; ++ni)
                acc[mi][ni] = __builtin_amdgcn_mfma_f32_16x16x32_bf16(
                    wf[ni], xf[mi], acc[mi][ni], 0, 0, 0);
    }

    // epilogue: D col(lane&15)=node, row((lane>>4)*4+reg)=feature; scale by dinv
#pragma unroll
    for (int mi = 0; mi < 4; ++mi) {
        int node = rowBase + nb + mi * 16 + lr;
        if (node < Nn) {
            float dv = dinv[node];
            uint* op = outb + (size_t)node * 64;
#pragma unroll
            for (int ni = 0; ni < 4; ++ni) {
                int fo = fb2 + ni * 16 + lk * 4;
                uint2 o;
                o.x = bf16rne(acc[mi][ni][0] * dv) | (bf16rne(acc[mi][ni][1] * dv) << 16);
                o.y = bf16rne(acc[mi][ni][2] * dv) | (bf16rne(acc[mi][ni][3] * dv) << 16);
                *(uint2*)(op + (fo >> 1)) = o;
            }
        }
    }
}

// ------- aggregation: agg[d] = dinv[d]*(sum_in h'[src] + h'[d]) + bias -------
// Proven loop shape (measured floor); src-only adjacency, self-loop direct.

__global__ __launch_bounds__(256) void k_agg(
    const uint* __restrict__ h32, const int* __restrict__ offs,
    const int* __restrict__ adj, const float* __restrict__ dinv,
    const float* __restrict__ bias, uint* __restrict__ agg,
    float* __restrict__ colsum) {
    __shared__ float ls[256];
    int tid = threadIdx.x;
    ls[tid] = 0.f;
    __syncthreads();
    int lane = tid & 63;
    int gw = blockIdx.x * 4 + (tid >> 6);
    int nw = NWAVES;
    int c0 = lane * 2;
    float b0 = bias[c0], b1 = bias[c0 + 1];
    float ps0 = 0.f, pq0 = 0.f, ps1 = 0.f, pq1 = 0.f;
    for (int d = gw; d < Nn; d += nw) {
        int beg = offs[d], end = offs[d + 1];
        float dvd = dinv[d];
        uint hself = h32[(size_t)d * 64 + lane];
        float a0 = bflo(hself), a1 = bfhi(hself);
        int i = beg;
        for (; i + 8 <= end; i += 8) {
            int e[8];
#pragma unroll
            for (int j = 0; j < 8; ++j) e[j] = adj[i + j];
            uint hv[8];
#pragma unroll
            for (int j = 0; j < 8; ++j)
                hv[j] = h32[(size_t)e[j] * 64 + lane];
#pragma unroll
            for (int j = 0; j < 8; ++j) {
                a0 += bflo(hv[j]);
                a1 += bfhi(hv[j]);
            }
        }
        for (; i < end; ++i) {
            uint hv = h32[(size_t)adj[i] * 64 + lane];
            a0 += bflo(hv);
            a1 += bfhi(hv);
        }
        a0 = fmaf(a0, dvd, b0);
        a1 = fmaf(a1, dvd, b1);
        agg[(size_t)d * 64 + lane] = bf16rne(a0) | (bf16rne(a1) << 16);
        ps0 += a0; pq0 += a0 * a0;
        ps1 += a1; pq1 += a1 * a1;
    }
    atomicAdd(&ls[c0], ps0);
    atomicAdd(&ls[c0 + 1], ps1);
    atomicAdd(&ls[128 + c0], pq0);
    atomicAdd(&ls[128 + c0 + 1], pq1);
    __syncthreads();
    atomicAdd(&colsum[tid], ls[tid]);
}

// ---------------- pool + linear (BN affine computed in-block) -------------

__global__ __launch_bounds__(256) void k_pool(
    const uint* __restrict__ agg, const int* __restrict__ batch,
    const float* __restrict__ cs, const float* __restrict__ gg,
    const float* __restrict__ be,
    const float* __restrict__ Wl, const float* __restrict__ bl,
    float* __restrict__ out) {
    __shared__ float scsh[256];
    int tid = threadIdx.x;
    if (tid < 128) {
        float s = cs[tid], q = cs[128 + tid];
        float m = s * (1.0f / Nn);
        float var = q * (1.0f / Nn) - m * m;
        float istd = rsqrtf(var + EPSb);
        float sc = istd * gg[tid];
        scsh[tid] = sc;
        scsh[128 + tid] = fmaf(-m, sc, be[tid]);
    }
    __syncthreads();
    int lane = tid & 63;
    int g = (blockIdx.x * blockDim.x + tid) >> 6;
    if (g >= Gg) return;
    int lo = 0, hi = Nn;
    while (lo < hi) { int mid = (lo + hi) >> 1; if (batch[mid] < g) lo = mid + 1; else hi = mid; }
    int beg = lo;
    hi = Nn;
    while (lo < hi) { int mid = (lo + hi) >> 1; if (batch[mid] < g + 1) lo = mid + 1; else hi = mid; }
    int end = lo;
    int c0 = lane * 2;
    float sc0 = scsh[c0], sh0 = scsh[128 + c0];
    float sc1 = scsh[c0 + 1], sh1 = scsh[128 + c0 + 1];
    float s0 = 0.f, s1 = 0.f;
    for (int n = beg; n < end; ++n) {
        uint v = agg[(size_t)n * 64 + lane];
        s0 += fmaxf(fmaf(bflo(v), sc0, sh0), 0.f);
        s1 += fmaxf(fmaf(bfhi(v), sc1, sh1), 0.f);
    }
    float inv = 1.0f / fmaxf((float)(end - beg), 1.0f);
    float part = (s0 * inv) * Wl[c0] + (s1 * inv) * Wl[c0 + 1];
#pragma unroll
    for (int off = 32; off; off >>= 1) part += __shfl_down(part, off);
    if (lane == 0) out[g] = part + bl[0];
}

// ---------------- launch --------------------------------------------------

extern "C" void kernel_launch(void* const* d_in, const int* in_sizes, int n_in,
                              void* d_out, int out_size, void* d_ws, size_t ws_size,
                              hipStream_t stream) {
    const float* x   = (const float*)d_in[0];
    const int*   ei  = (const int*)d_in[1];
    const int*   src = ei;
    const int*   dst = ei + Ee;
    const int*   bat = (const int*)d_in[2];
    const float* W1 = (const float*)d_in[3];
    const float* b1 = (const float*)d_in[4];
    const float* g1 = (const float*)d_in[5];
    const float* be1 = (const float*)d_in[6];
    const float* W2 = (const float*)d_in[7];
    const float* b2 = (const float*)d_in[8];
    const float* g2 = (const float*)d_in[9];
    const float* be2 = (const float*)d_in[10];
    const float* W3 = (const float*)d_in[11];
    const float* b3 = (const float*)d_in[12];
    const float* g3 = (const float*)d_in[13];
    const float* be3 = (const float*)d_in[14];
    const float* Wl = (const float*)d_in[15];
    const float* bl = (const float*)d_in[16];
    float* out = (float*)d_out;

    char* w = (char*)d_ws;
    auto alloc = [&](size_t bytes) {
        void* p = (void*)w;
        w += (bytes + 255) & ~(size_t)255;
        return p;
    };
    // deg, bcnt, colsum first and contiguous: one memset zeroes all three
    int*   deg    = (int*)alloc((size_t)Nn * 4);
    int*   bcnt   = (int*)alloc(BKT * 4);
    float* colsum = (float*)alloc(768 * 4);   // 3 layers x 256
    size_t zspan  = (size_t)((char*)(colsum + 768) - (char*)deg);
    int*   offs   = (int*)alloc((size_t)(Nn + 1) * 4);
    float* dinv   = (float*)alloc((size_t)Nn * 4);
    uint*  Wt     = (uint*)alloc((size_t)3 * 8192 * 4);
    uint*  stage  = (uint*)alloc((size_t)BKT * BSTRIDE * 4);   // 9.6 MB
    int*   adj    = (int*)alloc((size_t)Ee * 4);               // src-only, in-edges
    uint*  tmp    = (uint*)alloc((size_t)Nn * 64 * 4);    // bf16-packed h'
    uint*  agg    = (uint*)alloc((size_t)Nn * 64 * 4);    // bf16-packed agg

    float* csA = colsum;        // stats of agg1 (uses g1/be1)
    float* csB = colsum + 256;  // stats of agg2 (uses g2/be2)
    float* csC = colsum + 512;  // stats of agg3 (uses g3/be3)

    // graph preprocessing + weight conversion
    hipMemsetAsync(deg, 0, zspan, stream);
    k_bucket<<<FILL_BLOCKS, 256, 0, stream>>>(src, dst, deg, bcnt, stage);
    k_prep<<<BKT, 256, 0, stream>>>(deg, bcnt, stage, offs, dinv, adj);
    k_wconv3<<<96, 256, 0, stream>>>(W1, W2, W3, Wt);
    // layer 1
    k_gemm<<<GEMM_BLOCKS, 256, 0, stream>>>(x, (const uint*)0, Wt, dinv,
                                            (const float*)0, (const float*)0,
                                            (const float*)0, tmp, 0);
    k_agg<<<AGG_BLOCKS, 256, 0, stream>>>(tmp, offs, adj, dinv, b1, agg, csA);
    // layer 2
    k_gemm<<<GEMM_BLOCKS, 256, 0, stream>>>((const float*)0, agg, Wt + 8192, dinv,
                                            csA, g1, be1, tmp, 1);
    k_agg<<<AGG_BLOCKS, 256, 0, stream>>>(tmp, offs, adj, dinv, b2, agg, csB);
    // layer 3
    k_gemm<<<GEMM_BLOCKS, 256, 0, stream>>>((const float*)0, agg, Wt + 16384, dinv,
                                            csB, g2, be2, tmp, 1);
    k_agg<<<AGG_BLOCKS, 256, 0, stream>>>(tmp, offs, adj, dinv, b3, agg, csC);
    // pool + linear
    k_pool<<<(Gg * 64 + 255) / 256, 256, 0, stream>>>(agg, bat, csC, g3, be3,
                                                      Wl, bl, out);
}

// Round 15
// 540.905 us; speedup vs baseline: 1.0417x; 1.0417x over previous
//
#include <hip/hip_runtime.h>
#include <hip/hip_bf16.h>

#define Nn 100000
#define Ee 1600000
#define Hh 128
#define Gg 1000
#define EPSb 1e-5f

#define AGG_BLOCKS 2048
#define NWAVES (AGG_BLOCKS * 4)   // 8192
#define GEMM_BLOCKS 391     // x2 tiles each = 782 = ceil(100000/128)

#define BKT 196             // buckets = ceil(100000/512)
#define BSTRIDE 12288       // staging slots per bucket (mean 8163, +45 sigma)
#define FILL_CHUNK 4096
#define FILL_BLOCKS 391     // ceil(1600000/4096)

typedef unsigned int uint;
typedef short short8 __attribute__((ext_vector_type(8)));
typedef float floatx4 __attribute__((ext_vector_type(4)));

// round-to-nearest-even f32 -> bf16 (as low 16 bits of return)
static __device__ __forceinline__ uint bf16rne(float f) {
    uint u = __float_as_uint(f);
    return (u + 0x7fffu + ((u >> 16) & 1u)) >> 16;
}
static __device__ __forceinline__ float bflo(uint u) { return __uint_as_float(u << 16); }
static __device__ __forceinline__ float bfhi(uint u) { return __uint_as_float(u & 0xffff0000u); }

// ---------------- graph preprocessing ----------------
// deg/bcnt/colsum zeroed by one hipMemsetAsync. deg counted inside k_bucket.
// offs = CSR over in-edges only; self-loop handled in k_agg; dinv=rsqrt(deg+1).
// dinv factorization: GEMM pre-scales rows by dinv[src]; k_agg applies dinv[d].

// pass A: privatized counting sort by dst>>9 + per-node degree atomics.
__global__ __launch_bounds__(256) void k_bucket(
    const int* __restrict__ src, const int* __restrict__ dst,
    int* __restrict__ deg, int* __restrict__ bcnt, uint* __restrict__ stage) {
    __shared__ int cnt[BKT];
    __shared__ int base[BKT];
    int t = threadIdx.x;
    if (t < BKT) cnt[t] = 0;
    __syncthreads();
    int e0 = blockIdx.x * FILL_CHUNK;
    int slot[16], bkt[16];
#pragma unroll
    for (int j = 0; j < 16; ++j) {
        int i = e0 + j * 256 + t;
        if (i < Ee) {
            int dd = dst[i];
            atomicAdd(&deg[dd], 1);           // folded k_deg
            int b = dd >> 9;
            bkt[j] = b;
            slot[j] = atomicAdd(&cnt[b], 1);
        } else bkt[j] = -1;
    }
    __syncthreads();
    if (t < BKT) base[t] = atomicAdd(&bcnt[t], cnt[t]);
    __syncthreads();
#pragma unroll
    for (int j = 0; j < 16; ++j) {
        if (bkt[j] >= 0) {
            int i = e0 + j * 256 + t;
            int b = bkt[j];
            int p = base[b] + slot[j];
            if (p < BSTRIDE)
                stage[(size_t)b * BSTRIDE + p] =
                    (uint)src[i] | (((uint)dst[i] & 511u) << 17);
        }
    }
}

// prep: fused scan (offs + dinv) + scatter for one bucket (512 nodes).
// Bucket base = in-LDS scan of bcnt; local offs kept in LDS for the scatter.
__global__ __launch_bounds__(256) void k_prep(
    const int* __restrict__ deg, const int* __restrict__ bcnt,
    const uint* __restrict__ stage,
    int* __restrict__ offs, float* __restrict__ dinv, int* __restrict__ adj) {
    __shared__ int ls[256];
    __shared__ int bs[256];
    __shared__ int loffs[512];
    __shared__ int lcur[512];
    int t = threadIdx.x;
    int b = blockIdx.x;                 // bucket 0..195
    lcur[t] = 0; lcur[t + 256] = 0;
    bs[t] = (t < BKT) ? bcnt[t] : 0;
    int nEdges = bcnt[b];
    int base = (b << 9) + t * 2;        // 2 nodes per thread
    int d0 = (base     < Nn) ? deg[base]     : 0;
    int d1 = (base + 1 < Nn) ? deg[base + 1] : 0;
    int s = d0 + d1;
    ls[t] = s;
    __syncthreads();
    for (int off = 1; off < 256; off <<= 1) {
        int u0 = (t >= off) ? bs[t - off] : 0;
        int u1 = (t >= off) ? ls[t - off] : 0;
        __syncthreads();
        bs[t] += u0;
        ls[t] += u1;
        __syncthreads();
    }
    int bucketBase = (b == 0) ? 0 : bs[b - 1];
    int run = bucketBase + ls[t] - s;   // exclusive prefix
    loffs[t * 2] = run;
    if (base < Nn) {
        offs[base] = run;
        dinv[base] = rsqrtf((float)(d0 + 1));
    }
    run += d0;
    loffs[t * 2 + 1] = run;
    if (base + 1 < Nn) {
        offs[base + 1] = run;
        dinv[base + 1] = rsqrtf((float)(d1 + 1));
    }
    if (b == 0 && t == 0) offs[Nn] = Ee;
    __syncthreads();
    int n = nEdges > BSTRIDE ? BSTRIDE : nEdges;
    const uint* sp = stage + (size_t)b * BSTRIDE;
    for (int i = t; i < n; i += 256) {
        uint e = sp[i];
        int s2 = (int)(e & 0x1FFFFu);
        int dl = (int)(e >> 17);
        int pos = loffs[dl] + atomicAdd(&lcur[dl], 1);
        adj[pos] = s2;
    }
}

// ------- W conversion (all 3 layers): Wt[l][n][k/2] = bf16(W[k][n],W[k+1][n]) --

__global__ void k_wconv3(const float* __restrict__ W1, const float* __restrict__ W2,
                         const float* __restrict__ W3, uint* __restrict__ Wt) {
    int idx = blockIdx.x * blockDim.x + threadIdx.x;   // 3*8192
    if (idx >= 3 * 8192) return;
    const float* W = (idx < 8192) ? W1 : ((idx < 16384) ? W2 : W3);
    int k = idx & 8191;
    int n = k >> 6, ku = k & 63;
    uint lo = bf16rne(W[(size_t)(2 * ku) * 128 + n]);
    uint hi = bf16rne(W[(size_t)(2 * ku + 1) * 128 + n]);
    Wt[(size_t)(idx >> 13) * 8192 + n * 64 + ku] = lo | (hi << 16);
}

// ---------------- MFMA GEMM: tmp(bf16) = dinv[node] * (act(in) @ W) --------
// mode 0: in = fp32 x, identity act. mode 1: in = bf16 agg, act = relu(bn).
// 2 row-tiles per block: W staged once; tile-1 global loads issued before
// tile-0's MFMA (async-stage split). Epilogue scales rows by dinv[node].
// (r13-measured best GEMM form; r14's register-direct variant regressed.)

__global__ __launch_bounds__(256, 2) void k_gemm(
    const float* __restrict__ inf, const uint* __restrict__ inb,
    const uint* __restrict__ Wtp, const float* __restrict__ dinv,
    const float* __restrict__ cs, const float* __restrict__ gg,
    const float* __restrict__ be,
    uint* __restrict__ outb, int mode) {
    __shared__ uint XT[128][64];
    __shared__ uint WT[128][64];
    __shared__ float scsh[256];   // sc[128], sh[128]
    int t = threadIdx.x;
    int r = t >> 1, half = t & 1;

    if (mode && t < 128) {
        float s = cs[t], q = cs[128 + t];
        float m = s * (1.0f / Nn);
        float var = q * (1.0f / Nn) - m * m;
        float istd = rsqrtf(var + EPSb);
        float sc = istd * gg[t];
        scsh[t] = sc;
        scsh[128 + t] = fmaf(-m, sc, be[t]);
    }
    {   // stage W^T once (already packed bf16)
        const uint* sp = Wtp + (size_t)r * 64 + half * 32;
#pragma unroll
        for (int q = 0; q < 8; ++q) {
            uint4 v = *(const uint4*)(sp + q * 4);
            int g = half * 8 + q;
            *(uint4*)&WT[r][(g ^ (r & 7)) << 2] = v;
        }
    }

    float4 xf[16];   // mode-0 staging regs
    uint4  xb[8];    // mode-1 staging regs

    // ---- issue loads for tile 0 ----
    int rb0 = blockIdx.x * 128;
    {
        int grc = rb0 + r;
        if (grc >= Nn) grc = Nn - 1;
        if (mode == 0) {
            const float* sp = inf + (size_t)grc * 128 + half * 64;
#pragma unroll
            for (int q = 0; q < 8; ++q) {
                xf[2 * q]     = *(const float4*)(sp + q * 8);
                xf[2 * q + 1] = *(const float4*)(sp + q * 8 + 4);
            }
        } else {
            const uint* sp = inb + (size_t)grc * 64 + half * 32;
#pragma unroll
            for (int q = 0; q < 8; ++q) xb[q] = *(const uint4*)(sp + q * 4);
        }
    }
    __syncthreads();   // WT + scsh ready

    // ---- transform + write XT (tile 0) ----
#pragma unroll
    for (int q = 0; q < 8; ++q) {
        uint4 o;
        if (mode == 0) {
            float4 v0 = xf[2 * q], v1 = xf[2 * q + 1];
            o.x = bf16rne(v0.x) | (bf16rne(v0.y) << 16);
            o.y = bf16rne(v0.z) | (bf16rne(v0.w) << 16);
            o.z = bf16rne(v1.x) | (bf16rne(v1.y) << 16);
            o.w = bf16rne(v1.z) | (bf16rne(v1.w) << 16);
        } else {
            uint4 v = xb[q];
            int fb = half * 64 + q * 8;
            float av[8] = {bflo(v.x), bfhi(v.x), bflo(v.y), bfhi(v.y),
                           bflo(v.z), bfhi(v.z), bflo(v.w), bfhi(v.w)};
            uint oo[4];
#pragma unroll
            for (int k2 = 0; k2 < 4; ++k2) {
                float lo = fmaxf(fmaf(av[2 * k2], scsh[fb + 2 * k2],
                                      scsh[128 + fb + 2 * k2]), 0.f);
                float hi = fmaxf(fmaf(av[2 * k2 + 1], scsh[fb + 2 * k2 + 1],
                                      scsh[128 + fb + 2 * k2 + 1]), 0.f);
                oo[k2] = bf16rne(lo) | (bf16rne(hi) << 16);
            }
            o = make_uint4(oo[0], oo[1], oo[2], oo[3]);
        }
        int g = half * 8 + q;
        *(uint4*)&XT[r][(g ^ (r & 7)) << 2] = o;
    }
    __syncthreads();   // XT(tile0) ready

    int l = t & 63, w = t >> 6;
    int nb = (w >> 1) * 64;
    int fb2 = (w & 1) * 64;
    int lr = l & 15, lk = l >> 4;
    floatx4 zero = {0.f, 0.f, 0.f, 0.f};

    // ---- issue loads for tile 1 (hidden under tile-0 MFMA) ----
    int rb1 = (blockIdx.x + GEMM_BLOCKS) * 128;
    {
        int grc = rb1 + r;
        if (grc >= Nn) grc = Nn - 1;
        if (mode == 0) {
            const float* sp = inf + (size_t)grc * 128 + half * 64;
#pragma unroll
            for (int q = 0; q < 8; ++q) {
                xf[2 * q]     = *(const float4*)(sp + q * 8);
                xf[2 * q + 1] = *(const float4*)(sp + q * 8 + 4);
            }
        } else {
            const uint* sp = inb + (size_t)grc * 64 + half * 32;
#pragma unroll
            for (int q = 0; q < 8; ++q) xb[q] = *(const uint4*)(sp + q * 4);
        }
    }

    // ---- MFMA + store, tile 0 ----
    {
        floatx4 acc[4][4];
#pragma unroll
        for (int mi = 0; mi < 4; ++mi)
#pragma unroll
            for (int ni = 0; ni < 4; ++ni) acc[mi][ni] = zero;
#pragma unroll
        for (int kc = 0; kc < 4; ++kc) {
            short8 xfr[4], wfr[4];
            int g = kc * 4 + lk;
#pragma unroll
            for (int mi = 0; mi < 4; ++mi) {
                int rr = nb + mi * 16 + lr;
                xfr[mi] = *(const short8*)&XT[rr][(g ^ (rr & 7)) << 2];
            }
#pragma unroll
            for (int ni = 0; ni < 4; ++ni) {
                int rr = fb2 + ni * 16 + lr;
                wfr[ni] = *(const short8*)&WT[rr][(g ^ (rr & 7)) << 2];
            }
#pragma unroll
            for (int mi = 0; mi < 4; ++mi)
#pragma unroll
                for (int ni = 0; ni < 4; ++ni)
                    acc[mi][ni] = __builtin_amdgcn_mfma_f32_16x16x32_bf16(
                        wfr[ni], xfr[mi], acc[mi][ni], 0, 0, 0);
        }
#pragma unroll
        for (int mi = 0; mi < 4; ++mi) {
            int node = rb0 + nb + mi * 16 + lr;
            if (node < Nn) {
                float dv = dinv[node];
                uint* op = outb + (size_t)node * 64;
#pragma unroll
                for (int ni = 0; ni < 4; ++ni) {
                    int fo = fb2 + ni * 16 + lk * 4;
                    uint2 o;
                    o.x = bf16rne(acc[mi][ni][0] * dv) | (bf16rne(acc[mi][ni][1] * dv) << 16);
                    o.y = bf16rne(acc[mi][ni][2] * dv) | (bf16rne(acc[mi][ni][3] * dv) << 16);
                    *(uint2*)(op + (fo >> 1)) = o;
                }
            }
        }
    }
    __syncthreads();   // all XT(tile0) reads done

    // ---- transform + write XT (tile 1) ----
#pragma unroll
    for (int q = 0; q < 8; ++q) {
        uint4 o;
        if (mode == 0) {
            float4 v0 = xf[2 * q], v1 = xf[2 * q + 1];
            o.x = bf16rne(v0.x) | (bf16rne(v0.y) << 16);
            o.y = bf16rne(v0.z) | (bf16rne(v0.w) << 16);
            o.z = bf16rne(v1.x) | (bf16rne(v1.y) << 16);
            o.w = bf16rne(v1.z) | (bf16rne(v1.w) << 16);
        } else {
            uint4 v = xb[q];
            int fb = half * 64 + q * 8;
            float av[8] = {bflo(v.x), bfhi(v.x), bflo(v.y), bfhi(v.y),
                           bflo(v.z), bfhi(v.z), bflo(v.w), bfhi(v.w)};
            uint oo[4];
#pragma unroll
            for (int k2 = 0; k2 < 4; ++k2) {
                float lo = fmaxf(fmaf(av[2 * k2], scsh[fb + 2 * k2],
                                      scsh[128 + fb + 2 * k2]), 0.f);
                float hi = fmaxf(fmaf(av[2 * k2 + 1], scsh[fb + 2 * k2 + 1],
                                      scsh[128 + fb + 2 * k2 + 1]), 0.f);
                oo[k2] = bf16rne(lo) | (bf16rne(hi) << 16);
            }
            o = make_uint4(oo[0], oo[1], oo[2], oo[3]);
        }
        int g = half * 8 + q;
        *(uint4*)&XT[r][(g ^ (r & 7)) << 2] = o;
    }
    __syncthreads();   // XT(tile1) ready

    // ---- MFMA + store, tile 1 ----
    {
        floatx4 acc[4][4];
#pragma unroll
        for (int mi = 0; mi < 4; ++mi)
#pragma unroll
            for (int ni = 0; ni < 4; ++ni) acc[mi][ni] = zero;
#pragma unroll
        for (int kc = 0; kc < 4; ++kc) {
            short8 xfr[4], wfr[4];
            int g = kc * 4 + lk;
#pragma unroll
            for (int mi = 0; mi < 4; ++mi) {
                int rr = nb + mi * 16 + lr;
                xfr[mi] = *(const short8*)&XT[rr][(g ^ (rr & 7)) << 2];
            }
#pragma unroll
            for (int ni = 0; ni < 4; ++ni) {
                int rr = fb2 + ni * 16 + lr;
                wfr[ni] = *(const short8*)&WT[rr][(g ^ (rr & 7)) << 2];
            }
#pragma unroll
            for (int mi = 0; mi < 4; ++mi)
#pragma unroll
                for (int ni = 0; ni < 4; ++ni)
                    acc[mi][ni] = __builtin_amdgcn_mfma_f32_16x16x32_bf16(
                        wfr[ni], xfr[mi], acc[mi][ni], 0, 0, 0);
        }
#pragma unroll
        for (int mi = 0; mi < 4; ++mi) {
            int node = rb1 + nb + mi * 16 + lr;
            if (node < Nn) {
                float dv = dinv[node];
                uint* op = outb + (size_t)node * 64;
#pragma unroll
                for (int ni = 0; ni < 4; ++ni) {
                    int fo = fb2 + ni * 16 + lk * 4;
                    uint2 o;
                    o.x = bf16rne(acc[mi][ni][0] * dv) | (bf16rne(acc[mi][ni][1] * dv) << 16);
                    o.y = bf16rne(acc[mi][ni][2] * dv) | (bf16rne(acc[mi][ni][3] * dv) << 16);
                    *(uint2*)(op + (fo >> 1)) = o;
                }
            }
        }
    }
}

// ------- aggregation: agg[d] = dinv[d]*(sum_in h'[src] + h'[d]) + bias -------
// Proven loop shape (measured floor); src-only adjacency, self-loop direct.

__global__ __launch_bounds__(256) void k_agg(
    const uint* __restrict__ h32, const int* __restrict__ offs,
    const int* __restrict__ adj, const float* __restrict__ dinv,
    const float* __restrict__ bias, uint* __restrict__ agg,
    float* __restrict__ colsum) {
    __shared__ float ls[256];
    int tid = threadIdx.x;
    ls[tid] = 0.f;
    __syncthreads();
    int lane = tid & 63;
    int gw = blockIdx.x * 4 + (tid >> 6);
    int nw = NWAVES;
    int c0 = lane * 2;
    float b0 = bias[c0], b1 = bias[c0 + 1];
    float ps0 = 0.f, pq0 = 0.f, ps1 = 0.f, pq1 = 0.f;
    for (int d = gw; d < Nn; d += nw) {
        int beg = offs[d], end = offs[d + 1];
        float dvd = dinv[d];
        uint hself = h32[(size_t)d * 64 + lane];
        float a0 = bflo(hself), a1 = bfhi(hself);
        int i = beg;
        for (; i + 8 <= end; i += 8) {
            int e[8];
#pragma unroll
            for (int j = 0; j < 8; ++j) e[j] = adj[i + j];
            uint hv[8];
#pragma unroll
            for (int j = 0; j < 8; ++j)
                hv[j] = h32[(size_t)e[j] * 64 + lane];
#pragma unroll
            for (int j = 0; j < 8; ++j) {
                a0 += bflo(hv[j]);
                a1 += bfhi(hv[j]);
            }
        }
        for (; i < end; ++i) {
            uint hv = h32[(size_t)adj[i] * 64 + lane];
            a0 += bflo(hv);
            a1 += bfhi(hv);
        }
        a0 = fmaf(a0, dvd, b0);
        a1 = fmaf(a1, dvd, b1);
        agg[(size_t)d * 64 + lane] = bf16rne(a0) | (bf16rne(a1) << 16);
        ps0 += a0; pq0 += a0 * a0;
        ps1 += a1; pq1 += a1 * a1;
    }
    atomicAdd(&ls[c0], ps0);
    atomicAdd(&ls[c0 + 1], ps1);
    atomicAdd(&ls[128 + c0], pq0);
    atomicAdd(&ls[128 + c0 + 1], pq1);
    __syncthreads();
    atomicAdd(&colsum[tid], ls[tid]);
}

// ---------------- pool + linear (BN affine computed in-block) -------------

__global__ __launch_bounds__(256) void k_pool(
    const uint* __restrict__ agg, const int* __restrict__ batch,
    const float* __restrict__ cs, const float* __restrict__ gg,
    const float* __restrict__ be,
    const float* __restrict__ Wl, const float* __restrict__ bl,
    float* __restrict__ out) {
    __shared__ float scsh[256];
    int tid = threadIdx.x;
    if (tid < 128) {
        float s = cs[tid], q = cs[128 + tid];
        float m = s * (1.0f / Nn);
        float var = q * (1.0f / Nn) - m * m;
        float istd = rsqrtf(var + EPSb);
        float sc = istd * gg[tid];
        scsh[tid] = sc;
        scsh[128 + tid] = fmaf(-m, sc, be[tid]);
    }
    __syncthreads();
    int lane = tid & 63;
    int g = (blockIdx.x * blockDim.x + tid) >> 6;
    if (g >= Gg) return;
    int lo = 0, hi = Nn;
    while (lo < hi) { int mid = (lo + hi) >> 1; if (batch[mid] < g) lo = mid + 1; else hi = mid; }
    int beg = lo;
    hi = Nn;
    while (lo < hi) { int mid = (lo + hi) >> 1; if (batch[mid] < g + 1) lo = mid + 1; else hi = mid; }
    int end = lo;
    int c0 = lane * 2;
    float sc0 = scsh[c0], sh0 = scsh[128 + c0];
    float sc1 = scsh[c0 + 1], sh1 = scsh[128 + c0 + 1];
    float s0 = 0.f, s1 = 0.f;
    for (int n = beg; n < end; ++n) {
        uint v = agg[(size_t)n * 64 + lane];
        s0 += fmaxf(fmaf(bflo(v), sc0, sh0), 0.f);
        s1 += fmaxf(fmaf(bfhi(v), sc1, sh1), 0.f);
    }
    float inv = 1.0f / fmaxf((float)(end - beg), 1.0f);
    float part = (s0 * inv) * Wl[c0] + (s1 * inv) * Wl[c0 + 1];
#pragma unroll
    for (int off = 32; off; off >>= 1) part += __shfl_down(part, off);
    if (lane == 0) out[g] = part + bl[0];
}

// ---------------- launch --------------------------------------------------

extern "C" void kernel_launch(void* const* d_in, const int* in_sizes, int n_in,
                              void* d_out, int out_size, void* d_ws, size_t ws_size,
                              hipStream_t stream) {
    const float* x   = (const float*)d_in[0];
    const int*   ei  = (const int*)d_in[1];
    const int*   src = ei;
    const int*   dst = ei + Ee;
    const int*   bat = (const int*)d_in[2];
    const float* W1 = (const float*)d_in[3];
    const float* b1 = (const float*)d_in[4];
    const float* g1 = (const float*)d_in[5];
    const float* be1 = (const float*)d_in[6];
    const float* W2 = (const float*)d_in[7];
    const float* b2 = (const float*)d_in[8];
    const float* g2 = (const float*)d_in[9];
    const float* be2 = (const float*)d_in[10];
    const float* W3 = (const float*)d_in[11];
    const float* b3 = (const float*)d_in[12];
    const float* g3 = (const float*)d_in[13];
    const float* be3 = (const float*)d_in[14];
    const float* Wl = (const float*)d_in[15];
    const float* bl = (const float*)d_in[16];
    float* out = (float*)d_out;

    char* w = (char*)d_ws;
    auto alloc = [&](size_t bytes) {
        void* p = (void*)w;
        w += (bytes + 255) & ~(size_t)255;
        return p;
    };
    // deg, bcnt, colsum first and contiguous: one memset zeroes all three
    int*   deg    = (int*)alloc((size_t)Nn * 4);
    int*   bcnt   = (int*)alloc(BKT * 4);
    float* colsum = (float*)alloc(768 * 4);   // 3 layers x 256
    size_t zspan  = (size_t)((char*)(colsum + 768) - (char*)deg);
    int*   offs   = (int*)alloc((size_t)(Nn + 1) * 4);
    float* dinv   = (float*)alloc((size_t)Nn * 4);
    uint*  Wt     = (uint*)alloc((size_t)3 * 8192 * 4);
    uint*  stage  = (uint*)alloc((size_t)BKT * BSTRIDE * 4);   // 9.6 MB
    int*   adj    = (int*)alloc((size_t)Ee * 4);               // src-only, in-edges
    uint*  tmp    = (uint*)alloc((size_t)Nn * 64 * 4);    // bf16-packed h'
    uint*  agg    = (uint*)alloc((size_t)Nn * 64 * 4);    // bf16-packed agg

    float* csA = colsum;        // stats of agg1 (uses g1/be1)
    float* csB = colsum + 256;  // stats of agg2 (uses g2/be2)
    float* csC = colsum + 512;  // stats of agg3 (uses g3/be3)

    // graph preprocessing + weight conversion
    hipMemsetAsync(deg, 0, zspan, stream);
    k_bucket<<<FILL_BLOCKS, 256, 0, stream>>>(src, dst, deg, bcnt, stage);
    k_prep<<<BKT, 256, 0, stream>>>(deg, bcnt, stage, offs, dinv, adj);
    k_wconv3<<<96, 256, 0, stream>>>(W1, W2, W3, Wt);
    // layer 1
    k_gemm<<<GEMM_BLOCKS, 256, 0, stream>>>(x, (const uint*)0, Wt, dinv,
                                            (const float*)0, (const float*)0,
                                            (const float*)0, tmp, 0);
    k_agg<<<AGG_BLOCKS, 256, 0, stream>>>(tmp, offs, adj, dinv, b1, agg, csA);
    // layer 2
    k_gemm<<<GEMM_BLOCKS, 256, 0, stream>>>((const float*)0, agg, Wt + 8192, dinv,
                                            csA, g1, be1, tmp, 1);
    k_agg<<<AGG_BLOCKS, 256, 0, stream>>>(tmp, offs, adj, dinv, b2, agg, csB);
    // layer 3
    k_gemm<<<GEMM_BLOCKS, 256, 0, stream>>>((const float*)0, agg, Wt + 16384, dinv,
                                            csB, g2, be2, tmp, 1);
    k_agg<<<AGG_BLOCKS, 256, 0, stream>>>(tmp, offs, adj, dinv, b3, agg, csC);
    // pool + linear
    k_pool<<<(Gg * 64 + 255) / 256, 256, 0, stream>>>(agg, bat, csC, g3, be3,
                                                      Wl, bl, out);
}